// Round 9
// baseline (110.738 us; speedup 1.0000x reference)
//
#include <hip/hip_runtime.h>

#define BB 4096
#define TN 512
#define IN 13
#define HN 7
#define FFD 512
#define CT 16            // timesteps per chunk
#define NCK (TN / CT)    // 32 chunks
#define GPB 2            // chains per block

#if defined(__has_builtin)
#  if __has_builtin(__builtin_amdgcn_permlane16_swap)
#    define HAVE_PL16 1
#  endif
#endif

// quad broadcast (quad_perm): dst[l] = src[quadbase + q]
#define QB(v, q)    __int_as_float(__builtin_amdgcn_mov_dpp(__float_as_int(v), (q)*0x55, 0xF, 0xF, true))
// DPP row rotate by n lanes within each 16-lane row (direction probed at runtime)
#define RORF(v, n)  __int_as_float(__builtin_amdgcn_mov_dpp(__float_as_int(v), 0x120 + (n), 0xF, 0xF, true))

// Exchange 16-lane rows between a and b. MUST produce two DISTINCT registers:
// builtin returns a 2-vector (no coalescing possible); asm fallback forces
// distinct regs via early-clobber outputs.
__device__ __forceinline__ void rowswap(float& a, float& b) {
#ifdef HAVE_PL16
    auto r = __builtin_amdgcn_permlane16_swap(__float_as_uint(a), __float_as_uint(b),
                                              false, false);
    a = __uint_as_float(r[0]);
    b = __uint_as_float(r[1]);
#else
    float ta, tb;
    asm volatile("v_mov_b32 %0, %2\n"
                 "v_mov_b32 %1, %3\n"
                 "s_nop 1\n"
                 "v_permlane16_swap_b32 %0, %1"
                 : "=&v"(ta), "=&v"(tb)
                 : "v"(a), "v"(b));
    a = ta; b = tb;
#endif
}

// packed dual-fp32 FMA (CDNA2+): d.{x,y} = a.{x,y}*b.{x,y} + c.{x,y}
__device__ __forceinline__ float2 pkfma(float2 a, float2 b, float2 c) {
    float2 d;
    asm("v_pk_fma_f32 %0, %1, %2, %3" : "=v"(d) : "v"(a), "v"(b), "v"(c));
    return d;
}

__global__ __launch_bounds__(128, 4)
void lstm_fused(const float* __restrict__ x,
                const float* __restrict__ w_ih,
                const float* __restrict__ w_hh,
                const float* __restrict__ b_ih,
                const float* __restrict__ b_hh,
                const float* __restrict__ fc1_w,
                const float* __restrict__ fc1_b,
                const float* __restrict__ fc_w,
                const float* __restrict__ fc_b,
                float* __restrict__ out)
{
    __shared__ float2 xd2[2][CT/2][64];   // scaled gate pre-activation, step-pairs, dbuf
    __shared__ float  xs[IN][GPB][CT];    // staged x, COLUMN-major (col, chain, step)

    const int tid  = threadIdx.x;
    const int wid  = tid >> 6;            // 0 = consumer wave, 1 = producer wave
    const int l64  = tid & 63;
    const int grp  = l64 >> 5;
    const int lane = l64 & 31;
    const int b    = blockIdx.x * GPB + grp;

    // gate layout: quad j = hidden unit j, tau = lane&3 (0=i,1=f,2=g,3=o)
    const int tau = lane & 3;
    const int ju  = lane >> 2;
    const int jj  = (ju < HN) ? ju : (HN - 1);
    const int row = tau * HN + jj;
    const int jr  = ju & 3;

    const float L2E  = 1.4426950408889634f;
    const bool  is_tanh = (tau == 2);
    const float kmul = is_tanh ? (-2.0f * L2E) : (-L2E);  // folded into weights
    const float sc   = is_tanh ?  2.0f : 1.0f;
    const float offc = is_tanh ? -1.0f : 0.0f;

    // ---------------- runtime convention probes (one-time, all-VALU) ----------------
    // (a) row_ror direction: does RORF(v,4) give src[(l+4)&15] ("plus") or src[(l-4)&15]?
    const int pr = __builtin_amdgcn_mov_dpp(l64, 0x124, 0xF, 0xF, true);
    const bool ror_plus = ((pr & 15) == ((l64 + 4) & 15));
    // (b) rowswap family: probe with DISTINCT values so operands can't coalesce.
    float paf = __int_as_float(l64);
    float pbf = __int_as_float(l64 + 64);
    rowswap(paf, pbf);
    const int pa = __float_as_int(paf) & 63;            // source lane of a's value
    const bool a_even = (((pa >> 4) & 1) == 0);         // a holds even-16-row origin?

    // ---------------- producer-only state ----------------
    const int s_st = lane & 15;           // step this lane stages
    const int h_st = (lane >> 4) & 1;     // column half (0: cols 0-6, 1: cols 7-12)
    const int cb   = h_st * 7;
    float2 w2[IN];
    float2 bias2;
    float  p[7];

    // ---------------- consumer-only state ----------------
    // After rowswap + RORF(.,4k), slot k of the even-row family holds
    // h_{(jr + dk) & 3} with dk = ror_plus ? k : (4-k)&3; odd family same +4
    // (phantom index 7 -> weight 0).
    float wA[4], wB[4];

    if (wid == 1) {
#pragma unroll
        for (int i = 0; i < IN; ++i) {
            const float w = kmul * w_ih[row * IN + i];
            w2[i] = make_float2(w, w);
        }
        const float bsum = kmul * (b_ih[row] + b_hh[row]);
        bias2 = make_float2(bsum, bsum);
    } else {
#pragma unroll
        for (int k = 0; k < 4; ++k) {
            const int dk  = ror_plus ? k : ((4 - k) & 3);
            const int cL  = (jr + dk) & 3;          // low-family h index
            const int cH  = 4 + ((jr + dk) & 3);    // high-family h index (7 -> 0 weight)
            const float wL = kmul * w_hh[row * HN + cL];
            const float wH = (cH < HN) ? kmul * w_hh[row * HN + cH] : 0.0f;
            wA[k] = a_even ? wL : wH;
            wB[k] = a_even ? wH : wL;
        }
    }

    float a0 = 0.f, a1 = 0.f, a2 = 0.f, a3 = 0.f;
    float b0 = 0.f, b1 = 0.f, b2 = 0.f, b3 = 0.f;
    float cval = 0.0f;
    float hq_final = 0.0f;

    // ---------------- prologue: produce chunk 0, preload chunk 1 ----------------
    if (wid == 1) {
        const float* src0 = x + ((long)b * TN + s_st) * IN + cb;
#pragma unroll
        for (int c = 0; c < 6; ++c) p[c] = src0[c];
        if (h_st == 0) p[6] = src0[6];
#pragma unroll
        for (int c = 0; c < 6; ++c) xs[cb + c][grp][s_st] = p[c];
        if (h_st == 0) xs[cb + 6][grp][s_st] = p[6];
        {
            const float* src1 = x + ((long)b * TN + CT + s_st) * IN + cb;
#pragma unroll
            for (int c = 0; c < 6; ++c) p[c] = src1[c];
            if (h_st == 0) p[6] = src1[6];
        }
#pragma unroll
        for (int q = 0; q < CT; q += 4) {
            float2 accA = bias2, accB = bias2;
#pragma unroll
            for (int i = 0; i < IN; ++i) {
                const float4 xv = *(const float4*)&xs[i][grp][q];
                accA = pkfma(w2[i], make_float2(xv.x, xv.y), accA);
                accB = pkfma(w2[i], make_float2(xv.z, xv.w), accB);
            }
            xd2[0][(q >> 1) + 0][l64] = accA;
            xd2[0][(q >> 1) + 1][l64] = accB;
        }
    }
    __syncthreads();

    // ---------------- main pipeline ----------------
    for (int ck = 0; ck < NCK; ++ck) {
        if (wid == 1) {
            const int nk = ck + 1;                 // chunk to produce now
            if (nk < NCK) {
#pragma unroll
                for (int c = 0; c < 6; ++c) xs[cb + c][grp][s_st] = p[c];
                if (h_st == 0) xs[cb + 6][grp][s_st] = p[6];
                if (nk + 1 < NCK) {
                    const float* src = x + ((long)b * TN + (nk + 1) * CT + s_st) * IN + cb;
#pragma unroll
                    for (int c = 0; c < 6; ++c) p[c] = src[c];
                    if (h_st == 0) p[6] = src[6];
                }
                const int buf = nk & 1;
#pragma unroll
                for (int q = 0; q < CT; q += 4) {
                    float2 accA = bias2, accB = bias2;
#pragma unroll
                    for (int i = 0; i < IN; ++i) {
                        const float4 xv = *(const float4*)&xs[i][grp][q];
                        accA = pkfma(w2[i], make_float2(xv.x, xv.y), accA);
                        accB = pkfma(w2[i], make_float2(xv.z, xv.w), accB);
                    }
                    xd2[buf][(q >> 1) + 0][l64] = accA;
                    xd2[buf][(q >> 1) + 1][l64] = accB;
                }
            }
        } else {
            const int buf = ck & 1;
            float xr[CT];
#pragma unroll
            for (int pq = 0; pq < CT / 2; ++pq) {
                const float2 v = xd2[buf][pq][l64];
                xr[2 * pq]     = v.x;
                xr[2 * pq + 1] = v.y;
            }
#pragma unroll
            for (int s = 0; s < CT; ++s) {
                // gate pre-activation (pre-scaled by kmul): xr + h-dot, all registers
                float t0 = fmaf(wA[0], a0, xr[s]);
                t0 = fmaf(wA[1], a1, t0);
                t0 = fmaf(wA[2], a2, t0);
                t0 = fmaf(wA[3], a3, t0);
                float t1 = wB[0] * b0;
                t1 = fmaf(wB[1], b1, t1);
                t1 = fmaf(wB[2], b2, t1);
                t1 = fmaf(wB[3], b3, t1);
                const float sg = t0 + t1;

                float e   = __builtin_amdgcn_exp2f(sg);
                float val = fmaf(__builtin_amdgcn_rcpf(1.0f + e), sc, offc);

                const float iv = QB(val, 0);
                const float fv = QB(val, 1);
                const float gv = QB(val, 2);
                const float ov = QB(val, 3);

                cval = fmaf(fv, cval, iv * gv);
                float e2 = __builtin_amdgcn_exp2f(-2.0f * L2E * cval);
                float th = fmaf(__builtin_amdgcn_rcpf(1.0f + e2), 2.0f, -1.0f);
                const float hq = ov * th;
                hq_final = hq;

                // VALU-only h broadcast: rowswap (distinct regs) + 3 row rotations
                a0 = hq; b0 = hq;
                rowswap(a0, b0);
                a1 = RORF(a0, 4);
                a2 = RORF(a0, 8);
                a3 = RORF(a0, 12);
                b1 = RORF(b0, 4);
                b2 = RORF(b0, 8);
                b3 = RORF(b0, 12);
            }
        }
        __syncthreads();
    }

    if (wid == 1) return;

    // epilogue (consumer): relu -> fc1(512x7) -> relu -> fc(1x512)
    float hb[HN];
#pragma unroll
    for (int j = 0; j < HN; ++j) hb[j] = fmaxf(__shfl(hq_final, 4 * j, 32), 0.0f);

    float acc = 0.0f;
#pragma unroll
    for (int k = 0; k < FFD / 32; ++k) {
        const int r = lane + (k << 5);
        float s = fc1_b[r];
#pragma unroll
        for (int j = 0; j < HN; ++j) s = fmaf(fc1_w[r * HN + j], hb[j], s);
        s = fmaxf(s, 0.0f);
        acc = fmaf(fc_w[r], s, acc);
    }
#pragma unroll
    for (int o = 16; o >= 1; o >>= 1) acc += __shfl_xor(acc, o, 32);
    if (lane == 0) out[b] = acc + fc_b[0];
}

extern "C" void kernel_launch(void* const* d_in, const int* in_sizes, int n_in,
                              void* d_out, int out_size, void* d_ws, size_t ws_size,
                              hipStream_t stream) {
    const float* x     = (const float*)d_in[0];
    const float* w_ih  = (const float*)d_in[1];
    const float* w_hh  = (const float*)d_in[2];
    const float* b_ih  = (const float*)d_in[3];
    const float* b_hh  = (const float*)d_in[4];
    const float* fc1_w = (const float*)d_in[5];
    const float* fc1_b = (const float*)d_in[6];
    const float* fc_w  = (const float*)d_in[7];
    const float* fc_b  = (const float*)d_in[8];
    float* out = (float*)d_out;

    dim3 grid(BB / GPB);   // 2048 blocks x (1 consumer + 1 producer wave)
    dim3 block(128);
    hipLaunchKernelGGL(lstm_fused, grid, block, 0, stream,
                       x, w_ih, w_hh, b_ih, b_hh, fc1_w, fc1_b, fc_w, fc_b, out);
}

// Round 10
// 100.884 us; speedup vs baseline: 1.0977x; 1.0977x over previous
//
#include <hip/hip_runtime.h>

#define BB 4096
#define TN 512
#define IN 13
#define HN 7
#define FFD 512
#define CT 32            // timesteps per chunk
#define NCK (TN / CT)    // 16 chunks
#define GPB 2            // chains per block

#if defined(__has_builtin)
#  if __has_builtin(__builtin_amdgcn_permlane16_swap)
#    define HAVE_PL16 1
#  endif
#endif

// quad broadcast (quad_perm): dst[l] = src[quadbase + q]
#define QB(v, q)    __int_as_float(__builtin_amdgcn_mov_dpp(__float_as_int(v), (q)*0x55, 0xF, 0xF, true))
// DPP row rotate by n lanes within each 16-lane row (direction probed at runtime)
#define RORF(v, n)  __int_as_float(__builtin_amdgcn_mov_dpp(__float_as_int(v), 0x120 + (n), 0xF, 0xF, true))

// Exchange 16-lane rows between a and b -> two DISTINCT result registers.
__device__ __forceinline__ void rowswap(float& a, float& b) {
#ifdef HAVE_PL16
    auto r = __builtin_amdgcn_permlane16_swap(__float_as_uint(a), __float_as_uint(b),
                                              false, false);
    a = __uint_as_float(r[0]);
    b = __uint_as_float(r[1]);
#else
    float ta, tb;
    asm volatile("v_mov_b32 %0, %2\n"
                 "v_mov_b32 %1, %3\n"
                 "s_nop 1\n"
                 "v_permlane16_swap_b32 %0, %1"
                 : "=&v"(ta), "=&v"(tb)
                 : "v"(a), "v"(b));
    a = ta; b = tb;
#endif
}

// packed dual-fp32 FMA: d.{x,y} = a.{x,y}*b.{x,y} + c.{x,y}
__device__ __forceinline__ float2 pkfma(float2 a, float2 b, float2 c) {
    float2 d;
    asm("v_pk_fma_f32 %0, %1, %2, %3" : "=v"(d) : "v"(a), "v"(b), "v"(c));
    return d;
}

__global__ __launch_bounds__(128, 4)
void lstm_fused(const float* __restrict__ x,
                const float* __restrict__ w_ih,
                const float* __restrict__ w_hh,
                const float* __restrict__ b_ih,
                const float* __restrict__ b_hh,
                const float* __restrict__ fc1_w,
                const float* __restrict__ fc1_b,
                const float* __restrict__ fc_w,
                const float* __restrict__ fc_b,
                float* __restrict__ out)
{
    __shared__ float2 xd2[2][CT/2][64];   // scaled gate pre-activation, step-pairs, dbuf (16 KB)
    __shared__ float  xs[IN][GPB][CT];    // staged x, COLUMN-major (col, chain, step) (3.3 KB)

    const int tid  = threadIdx.x;
    const int wid  = tid >> 6;            // 0 = consumer wave, 1 = producer wave
    const int l64  = tid & 63;
    const int grp  = l64 >> 5;
    const int lane = l64 & 31;
    const int b    = blockIdx.x * GPB + grp;

    // gate layout: quad j = hidden unit j, tau = lane&3 (0=i,1=f,2=g,3=o)
    const int tau = lane & 3;
    const int ju  = lane >> 2;
    const int jj  = (ju < HN) ? ju : (HN - 1);
    const int row = tau * HN + jj;
    const int jr  = ju & 3;

    const float L2E  = 1.4426950408889634f;
    const bool  is_tanh = (tau == 2);
    const float kmul = is_tanh ? (-2.0f * L2E) : (-L2E);  // folded into weights
    const float sc   = is_tanh ?  2.0f : 1.0f;
    const float offc = is_tanh ? -1.0f : 0.0f;

    // ---------------- runtime convention probes (one-time, all-VALU) ----------------
    const int pr = __builtin_amdgcn_mov_dpp(l64, 0x124, 0xF, 0xF, true);
    const bool ror_plus = ((pr & 15) == ((l64 + 4) & 15));
    float paf = __int_as_float(l64);
    float pbf = __int_as_float(l64 + 64);
    rowswap(paf, pbf);
    const int pa = __float_as_int(paf) & 63;
    const bool a_even = (((pa >> 4) & 1) == 0);

    // ---------------- producer-only state ----------------
    float2 w2[IN];
    float2 bias2;
    float  p[IN];                         // one full x-row (this lane's step)
    const float* xbase = x + (long)b * TN * IN;

    // ---------------- consumer-only state ----------------
    float wA[4], wB[4];

    if (wid == 1) {
#pragma unroll
        for (int i = 0; i < IN; ++i) {
            const float w = kmul * w_ih[row * IN + i];
            w2[i] = make_float2(w, w);
        }
        const float bsum = kmul * (b_ih[row] + b_hh[row]);
        bias2 = make_float2(bsum, bsum);
    } else {
#pragma unroll
        for (int k = 0; k < 4; ++k) {
            const int dk  = ror_plus ? k : ((4 - k) & 3);
            const int cL  = (jr + dk) & 3;
            const int cH  = 4 + ((jr + dk) & 3);
            const float wL = kmul * w_hh[row * HN + cL];
            const float wH = (cH < HN) ? kmul * w_hh[row * HN + cH] : 0.0f;
            wA[k] = a_even ? wL : wH;
            wB[k] = a_even ? wH : wL;
        }
    }

    float a0 = 0.f, a1 = 0.f, a2 = 0.f, a3 = 0.f;
    float b0 = 0.f, b1 = 0.f, b2 = 0.f, b3 = 0.f;
    float cval = 0.0f;
    float hq_final = 0.0f;

    // producer micro-ops
#define LOADP(ck) do {                                                        \
        const float* _s = xbase + (long)((ck) * CT + lane) * IN;              \
        _Pragma("unroll")                                                     \
        for (int _i = 0; _i < IN; ++_i) p[_i] = _s[_i];                       \
    } while (0)
#define COMMITP() do {                                                        \
        _Pragma("unroll")                                                     \
        for (int _i = 0; _i < IN; ++_i) xs[_i][grp][lane] = p[_i];            \
    } while (0)
#define PROJECT(ck) do {                                                      \
        const int _buf = (ck) & 1;                                            \
        _Pragma("unroll")                                                     \
        for (int _q = 0; _q < CT; _q += 4) {                                  \
            float2 _aA = bias2, _aB = bias2;                                  \
            _Pragma("unroll")                                                 \
            for (int _i = 0; _i < IN; ++_i) {                                 \
                const float4 _xv = *(const float4*)&xs[_i][grp][_q];          \
                _aA = pkfma(w2[_i], make_float2(_xv.x, _xv.y), _aA);          \
                _aB = pkfma(w2[_i], make_float2(_xv.z, _xv.w), _aB);          \
            }                                                                 \
            xd2[_buf][(_q >> 1) + 0][l64] = _aA;                              \
            xd2[_buf][(_q >> 1) + 1][l64] = _aB;                              \
        }                                                                     \
    } while (0)

    // relaxed barrier: producer drains LDS ops; vmcnt (prefetch) stays in flight
#define HANDOFF() do {                                                        \
        if (wid == 1) { asm volatile("s_waitcnt lgkmcnt(0)" ::: "memory"); }  \
        __builtin_amdgcn_sched_barrier(0);                                    \
        __builtin_amdgcn_s_barrier();                                         \
        __builtin_amdgcn_sched_barrier(0);                                    \
    } while (0)

    // ---------------- prologue ----------------
    if (wid == 1) {
        LOADP(0);
        COMMITP();
        LOADP(1);          // prefetch chunk 1 (register dep handled by compiler)
        PROJECT(0);
    }
    HANDOFF();

    // ---------------- main pipeline ----------------
    for (int ck = 0; ck < NCK; ++ck) {
        if (wid == 1) {
            const int nk = ck + 1;
            if (nk < NCK) {
                COMMITP();                     // p holds chunk nk
                if (nk + 1 < NCK) LOADP(nk + 1);
                PROJECT(nk);
            }
        } else {
            const int buf = ck & 1;
            float2 xr2[CT / 2];
#pragma unroll
            for (int pq = 0; pq < CT / 2; ++pq) xr2[pq] = xd2[buf][pq][l64];

#pragma unroll
            for (int s = 0; s < CT; ++s) {
                const float xr = (s & 1) ? xr2[s >> 1].y : xr2[s >> 1].x;
                float t0 = fmaf(wA[0], a0, xr);
                t0 = fmaf(wA[1], a1, t0);
                t0 = fmaf(wA[2], a2, t0);
                t0 = fmaf(wA[3], a3, t0);
                float t1 = wB[0] * b0;
                t1 = fmaf(wB[1], b1, t1);
                t1 = fmaf(wB[2], b2, t1);
                t1 = fmaf(wB[3], b3, t1);
                const float sg = t0 + t1;

                float e   = __builtin_amdgcn_exp2f(sg);
                float val = fmaf(__builtin_amdgcn_rcpf(1.0f + e), sc, offc);

                const float iv = QB(val, 0);
                const float fv = QB(val, 1);
                const float gv = QB(val, 2);
                const float ov = QB(val, 3);

                cval = fmaf(fv, cval, iv * gv);
                float e2 = __builtin_amdgcn_exp2f(-2.0f * L2E * cval);
                float th = fmaf(__builtin_amdgcn_rcpf(1.0f + e2), 2.0f, -1.0f);
                const float hq = ov * th;
                hq_final = hq;

                a0 = hq; b0 = hq;
                rowswap(a0, b0);
                a1 = RORF(a0, 4);
                a2 = RORF(a0, 8);
                a3 = RORF(a0, 12);
                b1 = RORF(b0, 4);
                b2 = RORF(b0, 8);
                b3 = RORF(b0, 12);
            }
        }
        HANDOFF();
    }

    if (wid == 1) return;

    // epilogue (consumer): relu -> fc1(512x7) -> relu -> fc(1x512)
    float hb[HN];
#pragma unroll
    for (int j = 0; j < HN; ++j) hb[j] = fmaxf(__shfl(hq_final, 4 * j, 32), 0.0f);

    float acc = 0.0f;
#pragma unroll
    for (int k = 0; k < FFD / 32; ++k) {
        const int r = lane + (k << 5);
        float s = fc1_b[r];
#pragma unroll
        for (int j = 0; j < HN; ++j) s = fmaf(fc1_w[r * HN + j], hb[j], s);
        s = fmaxf(s, 0.0f);
        acc = fmaf(fc_w[r], s, acc);
    }
#pragma unroll
    for (int o = 16; o >= 1; o >>= 1) acc += __shfl_xor(acc, o, 32);
    if (lane == 0) out[b] = acc + fc_b[0];
}

extern "C" void kernel_launch(void* const* d_in, const int* in_sizes, int n_in,
                              void* d_out, int out_size, void* d_ws, size_t ws_size,
                              hipStream_t stream) {
    const float* x     = (const float*)d_in[0];
    const float* w_ih  = (const float*)d_in[1];
    const float* w_hh  = (const float*)d_in[2];
    const float* b_ih  = (const float*)d_in[3];
    const float* b_hh  = (const float*)d_in[4];
    const float* fc1_w = (const float*)d_in[5];
    const float* fc1_b = (const float*)d_in[6];
    const float* fc_w  = (const float*)d_in[7];
    const float* fc_b  = (const float*)d_in[8];
    float* out = (float*)d_out;

    dim3 grid(BB / GPB);   // 2048 blocks x (1 consumer + 1 producer wave)
    dim3 block(128);
    hipLaunchKernelGGL(lstm_fused, grid, block, 0, stream,
                       x, w_ih, w_hh, b_ih, b_hh, fc1_w, fc1_b, fc_w, fc_b, out);
}